// Round 2
// baseline (627.407 us; speedup 1.0000x reference)
//
#include <hip/hip_runtime.h>

// HiddenMarkovGFormulaV2: N independent sequential filters over T=64 steps.
// Memory-bound streaming (~518 MB ideal -> ~82 us floor at 6.3 TB/s).
//
// R1 was latency-bound (2.36 TB/s, occ 28%): 50KB LDS -> 3 blocks/CU and
// barrier-exposed load latency. R2: CT=8 (25KB LDS -> 5-6 blocks/CU) +
// register software-prefetch of tile k+1 during compute of tile k + leaner
// per-step math (1 log, 1 rcp for posterior var, folded affine constants).

#define TT 64          // timesteps (fixed by reference)
#define KK 3           // covariates (fixed by reference)
#define NB 256         // individuals per block == block size
#define CT 8           // timesteps per LDS tile
#define NTILES (TT / CT)
#define LDP (NB + 4)   // 260: bank = (4t + n) mod 32 -> 2-way (free)

__global__ void zero_ll_kernel(float* ll) { *ll = 0.0f; }

__global__ __launch_bounds__(NB) void hmm_filter_kernel(
    const float* __restrict__ G,   // (N,1)
    const float* __restrict__ S,   // (N,T)
    const float* __restrict__ C,   // (N,T)
    const float* __restrict__ Y,   // (N,T)
    const float* __restrict__ L,   // (N,K)
    const float* __restrict__ p_psi,
    const float* __restrict__ p_gS,
    const float* __restrict__ p_gC,
    const float* __restrict__ p_gG,
    const float* __restrict__ p_gGS,
    const float* __restrict__ p_gGC,
    const float* __restrict__ p_gLw,  // (1,K)
    const float* __restrict__ p_lsZ,
    const float* __restrict__ p_b0,
    const float* __restrict__ p_bZ,
    const float* __restrict__ p_bS,
    const float* __restrict__ p_bG,
    const float* __restrict__ p_bGS,
    const float* __restrict__ p_bLw,  // (1,K)
    float* __restrict__ Zf,           // (N,T)
    float* __restrict__ Zv,           // (N,T)
    float* __restrict__ ll_out,       // scalar
    int N)
{
    __shared__ float sS[CT][LDP];
    __shared__ float sC[CT][LDP];
    __shared__ float sY[CT][LDP];
    __shared__ float wave_ll[NB / 64];

    const int tid = threadIdx.x;
    const int n0  = blockIdx.x * NB;
    const int n   = n0 + tid;
    const bool valid = (n < N);
    const float vmask = valid ? 1.0f : 0.0f;

    // --- uniform parameters ---
    const float psi  = p_psi[0];
    const float gS   = p_gS[0];
    const float gC   = p_gC[0];
    const float gG   = p_gG[0];
    const float gGS  = p_gGS[0];
    const float gGC  = p_gGC[0];
    const float b0   = p_b0[0];
    const float bZ   = p_bZ[0];
    const float bS   = p_bS[0];
    const float bG   = p_bG[0];
    const float bGS  = p_bGS[0];
    const float esz  = __expf(p_lsZ[0]);
    const float sigma2 = esz * esz;
    const float psi2 = psi * psi;
    const float bZ2  = bZ * bZ;
    const float gw0 = p_gLw[0], gw1 = p_gLw[1], gw2 = p_gLw[2];
    const float bw0 = p_bLw[0], bw1 = p_bLw[1], bw2 = p_bLw[2];

    // --- per-thread constants (fold G and L terms into affine coeffs) ---
    float Gv = 0.0f, gL = 0.0f, bL = 0.0f;
    if (valid) {
        Gv = G[n];
        const float l0 = L[n * KK + 0];
        const float l1 = L[n * KK + 1];
        const float l2 = L[n * KK + 2];
        gL = l0 * gw0 + l1 * gw1 + l2 * gw2;
        bL = l0 * bw0 + l1 * bw1 + l2 * bw2;
    }
    const float aS = gS + gGS * Gv;          // coeff of s in zpred
    const float aC = gC + gGC * Gv;          // coeff of c in zpred
    const float a0 = gG * Gv + gL;           // const in zpred
    const float lS = bS + bGS * Gv;          // coeff of s in logit (excl bZ*zpred)
    const float l0c = b0 + bG * Gv + bL;     // const in logit

    float zm = 0.0f;   // Z_mean
    float zv = 1.0f;   // Z_var
    float ll = 0.0f;

    const float4* S4 = (const float4*)S;
    const float4* C4 = (const float4*)C;
    const float4* Y4 = (const float4*)Y;
    float4* Zf4 = (float4*)Zf;
    float4* Zv4 = (float4*)Zv;

    // cooperative-load mapping: tile has NB rows x CT floats = NB*CT/4 float4s.
    // j in {0,1}: q = tid + j*NB; r = q>>1 (row), c = q&1 (which float4).
    const int r0 = tid >> 1,          c0 = tid & 1;
    const int r1 = (tid + NB) >> 1,   c1 = c0;   // (tid+256)&1 == tid&1
    const int nn0 = n0 + r0, nn1 = n0 + r1;
    const bool v0 = (nn0 < N), v1 = (nn1 < N);

    // --- prefetch tile 0 into registers ---
    float4 rs0, rs1, rc0, rc1, ry0, ry1;
    {
        const float4 z4 = make_float4(0, 0, 0, 0);
        const int g0 = nn0 * (TT / 4) + c0;
        const int g1 = nn1 * (TT / 4) + c1;
        rs0 = v0 ? S4[g0] : z4;  rc0 = v0 ? C4[g0] : z4;  ry0 = v0 ? Y4[g0] : z4;
        rs1 = v1 ? S4[g1] : z4;  rc1 = v1 ? C4[g1] : z4;  ry1 = v1 ? Y4[g1] : z4;
    }

    for (int k = 0; k < NTILES; ++k) {
        const int t0 = k * CT;
        __syncthreads();   // previous tile's store-phase LDS readers done

        // --- scatter prefetched registers -> transposed LDS ---
        {
            const int tb0 = c0 * 4, tb1 = c1 * 4;
            sS[tb0 + 0][r0] = rs0.x; sS[tb0 + 1][r0] = rs0.y;
            sS[tb0 + 2][r0] = rs0.z; sS[tb0 + 3][r0] = rs0.w;
            sC[tb0 + 0][r0] = rc0.x; sC[tb0 + 1][r0] = rc0.y;
            sC[tb0 + 2][r0] = rc0.z; sC[tb0 + 3][r0] = rc0.w;
            sY[tb0 + 0][r0] = ry0.x; sY[tb0 + 1][r0] = ry0.y;
            sY[tb0 + 2][r0] = ry0.z; sY[tb0 + 3][r0] = ry0.w;
            sS[tb1 + 0][r1] = rs1.x; sS[tb1 + 1][r1] = rs1.y;
            sS[tb1 + 2][r1] = rs1.z; sS[tb1 + 3][r1] = rs1.w;
            sC[tb1 + 0][r1] = rc1.x; sC[tb1 + 1][r1] = rc1.y;
            sC[tb1 + 2][r1] = rc1.z; sC[tb1 + 3][r1] = rc1.w;
            sY[tb1 + 0][r1] = ry1.x; sY[tb1 + 1][r1] = ry1.y;
            sY[tb1 + 2][r1] = ry1.z; sY[tb1 + 3][r1] = ry1.w;
        }
        __syncthreads();

        // --- issue next tile's global loads (latency hidden by compute) ---
        if (k + 1 < NTILES) {
            const float4 z4 = make_float4(0, 0, 0, 0);
            const int tf = (t0 + CT) >> 2;
            const int g0 = nn0 * (TT / 4) + tf + c0;
            const int g1 = nn1 * (TT / 4) + tf + c1;
            rs0 = v0 ? S4[g0] : z4;  rc0 = v0 ? C4[g0] : z4;  ry0 = v0 ? Y4[g0] : z4;
            rs1 = v1 ? S4[g1] : z4;  rc1 = v1 ? C4[g1] : z4;  ry1 = v1 ? Y4[g1] : z4;
        }

        // --- sequential filter over CT steps; stage outputs in place ---
        #pragma unroll
        for (int t = 0; t < CT; ++t) {
            const float s = sS[t][tid];
            const float c = sC[t][tid];
            const float y = sY[t][tid];

            const float zpred = fmaf(psi, zm, fmaf(aS, s, fmaf(aC, c, a0)));
            const float zpvar = fmaf(psi2, zv, sigma2);

            float logit = fmaf(bZ, zpred, fmaf(lS, s, l0c));
            logit = fminf(fmaxf(logit, -20.0f), 20.0f);
            const float p = __builtin_amdgcn_rcpf(1.0f + __expf(-logit));

            const float grad = (y - p) * bZ;
            const float hess = fmaf(bZ2, p * (1.0f - p), 1e-6f);
            const float zvn = zpvar * __builtin_amdgcn_rcpf(fmaf(zpvar, hess, 1.0f));
            const float zmn = fmaf(zvn, grad, zpred);

            // y in {0,1} exactly: y*log(p+e) + (1-y)*log(1-p+e) == log((y?p:1-p)+e)
            const float sel = fmaf(y, fmaf(2.0f, p, -1.0f), 1.0f - p); // y?p:1-p
            ll = fmaf(vmask, __logf(sel + 1e-10f), ll);

            zm = zmn;
            zv = zvn;
            sS[t][tid] = zmn;   // stage Z_filtered
            sC[t][tid] = zvn;   // stage Z_variance
        }
        __syncthreads();

        // --- cooperative coalesced store of staged outputs ---
        {
            const int tf = t0 >> 2;
            if (v0) {
                const int tb = c0 * 4;
                float4 vf, vv;
                vf.x = sS[tb + 0][r0]; vf.y = sS[tb + 1][r0];
                vf.z = sS[tb + 2][r0]; vf.w = sS[tb + 3][r0];
                vv.x = sC[tb + 0][r0]; vv.y = sC[tb + 1][r0];
                vv.z = sC[tb + 2][r0]; vv.w = sC[tb + 3][r0];
                const int g = nn0 * (TT / 4) + tf + c0;
                Zf4[g] = vf; Zv4[g] = vv;
            }
            if (v1) {
                const int tb = c1 * 4;
                float4 vf, vv;
                vf.x = sS[tb + 0][r1]; vf.y = sS[tb + 1][r1];
                vf.z = sS[tb + 2][r1]; vf.w = sS[tb + 3][r1];
                vv.x = sC[tb + 0][r1]; vv.y = sC[tb + 1][r1];
                vv.z = sC[tb + 2][r1]; vv.w = sC[tb + 3][r1];
                const int g = nn1 * (TT / 4) + tf + c1;
                Zf4[g] = vf; Zv4[g] = vv;
            }
        }
    }

    // --- log-likelihood: wave shuffle -> LDS -> one atomic per block ---
    #pragma unroll
    for (int off = 32; off > 0; off >>= 1) {
        ll += __shfl_down(ll, off, 64);
    }
    __syncthreads();   // LDS reuse safety (wave_ll aliases nothing, but order)
    const int wid  = tid >> 6;
    const int lane = tid & 63;
    if (lane == 0) wave_ll[wid] = ll;
    __syncthreads();
    if (tid == 0) {
        float ssum = 0.0f;
        #pragma unroll
        for (int w = 0; w < NB / 64; ++w) ssum += wave_ll[w];
        atomicAdd(ll_out, ssum);
    }
}

extern "C" void kernel_launch(void* const* d_in, const int* in_sizes, int n_in,
                              void* d_out, int out_size, void* d_ws, size_t ws_size,
                              hipStream_t stream) {
    const int N = in_sizes[0];  // G is (N,1)

    const float* G   = (const float*)d_in[0];
    const float* S   = (const float*)d_in[1];
    const float* C   = (const float*)d_in[2];
    const float* Y   = (const float*)d_in[3];
    const float* L   = (const float*)d_in[4];
    const float* psi = (const float*)d_in[5];
    const float* gS  = (const float*)d_in[6];
    const float* gC  = (const float*)d_in[7];
    const float* gG  = (const float*)d_in[8];
    const float* gGS = (const float*)d_in[9];
    const float* gGC = (const float*)d_in[10];
    const float* gLw = (const float*)d_in[11];
    const float* lsZ = (const float*)d_in[12];
    const float* b0  = (const float*)d_in[13];
    const float* bZ  = (const float*)d_in[14];
    const float* bS  = (const float*)d_in[15];
    const float* bG  = (const float*)d_in[16];
    const float* bGS = (const float*)d_in[17];
    const float* bLw = (const float*)d_in[18];

    float* out = (float*)d_out;
    float* Zf = out;
    float* Zv = out + (size_t)N * TT;
    float* ll = out + (size_t)2 * N * TT;

    zero_ll_kernel<<<1, 1, 0, stream>>>(ll);

    const int blocks = (N + NB - 1) / NB;
    hmm_filter_kernel<<<blocks, NB, 0, stream>>>(
        G, S, C, Y, L, psi, gS, gC, gG, gGS, gGC, gLw, lsZ,
        b0, bZ, bS, bG, bGS, bLw, Zf, Zv, ll, N);
}

// Round 3
// 531.866 us; speedup vs baseline: 1.1796x; 1.1796x over previous
//
#include <hip/hip_runtime.h>

// HiddenMarkovGFormulaV2: N independent sequential filters over T=64 steps.
// Memory-bound streaming (~518 MB ideal -> ~82 us floor at 6.3 TB/s).
//
// R1 (CT=16, 3 LDS arrays, 50KB): perfect traffic (513MB) but 3 blocks/CU,
//    latency-bound at 2.36 TB/s.
// R2 (CT=8): occupancy 45% but FETCH 2.13x (32B/row/tile = half a 64B HBM
//    line, second half evicted from L2 between tiles) -> regression.
// R3: CT=16 (full-line fetch) + pack S,Y (both exactly {0,1}) into one LDS
//    plane as S+2Y -> 2 planes x 16KB = exactly 32KB LDS -> 5 blocks/CU,
//    62.5% occupancy. XOR swizzle (no pad) keeps every LDS access 2-way
//    (free). Register prefetch of tile k+1 during compute of tile k.

#define TT 64          // timesteps (fixed by reference)
#define KK 3           // covariates (fixed by reference)
#define NB 256         // individuals per block == block size
#define CT 16          // timesteps per LDS tile
#define NTILES (TT / CT)

__global__ void zero_ll_kernel(float* ll) { *ll = 0.0f; }

__global__ __launch_bounds__(NB, 5) void hmm_filter_kernel(
    const float* __restrict__ G,   // (N,1)
    const float* __restrict__ S,   // (N,T)
    const float* __restrict__ C,   // (N,T)
    const float* __restrict__ Y,   // (N,T)
    const float* __restrict__ L,   // (N,K)
    const float* __restrict__ p_psi,
    const float* __restrict__ p_gS,
    const float* __restrict__ p_gC,
    const float* __restrict__ p_gG,
    const float* __restrict__ p_gGS,
    const float* __restrict__ p_gGC,
    const float* __restrict__ p_gLw,  // (1,K)
    const float* __restrict__ p_lsZ,
    const float* __restrict__ p_b0,
    const float* __restrict__ p_bZ,
    const float* __restrict__ p_bS,
    const float* __restrict__ p_bG,
    const float* __restrict__ p_bGS,
    const float* __restrict__ p_bLw,  // (1,K)
    float* __restrict__ Zf,           // (N,T)
    float* __restrict__ Zv,           // (N,T)
    float* __restrict__ ll_out,       // scalar
    int N)
{
    // Two LDS planes, CT x NB each, 16 KB each -> exactly 32 KB total.
    // Logical slot (t, r) lives at t*NB + (r ^ (16*((t>>2)&1))).
    // Bank checks (all 2 lanes/bank = free, m136):
    //   compute read/write [t*NB + (tid^xc)]: permutation of lanes.
    //   scatter/gather (c=lane&3, r=lane>>2+64j): bank=(lane>>2)^(16*(lane&1)).
    __shared__ float sbuf[CT * NB];   // packed S+2Y, then staged Z_filtered
    __shared__ float cbuf[CT * NB];   // C, then staged Z_variance

    const int tid = threadIdx.x;
    const int n0  = blockIdx.x * NB;
    const int n   = n0 + tid;
    const bool valid = (n < N);

    // --- uniform parameters ---
    const float psi  = p_psi[0];
    const float gS   = p_gS[0];
    const float gC   = p_gC[0];
    const float gG   = p_gG[0];
    const float gGS  = p_gGS[0];
    const float gGC  = p_gGC[0];
    const float b0   = p_b0[0];
    const float bZ   = p_bZ[0];
    const float bS   = p_bS[0];
    const float bG   = p_bG[0];
    const float bGS  = p_bGS[0];
    const float esz  = __expf(p_lsZ[0]);
    const float sigma2 = esz * esz;
    const float psi2 = psi * psi;
    const float bZ2  = bZ * bZ;
    const float gw0 = p_gLw[0], gw1 = p_gLw[1], gw2 = p_gLw[2];
    const float bw0 = p_bLw[0], bw1 = p_bLw[1], bw2 = p_bLw[2];

    // --- per-thread constants (fold G and L terms into affine coeffs) ---
    float Gv = 0.0f, gL = 0.0f, bL = 0.0f;
    if (valid) {
        Gv = G[n];
        const float l0 = L[n * KK + 0];
        const float l1 = L[n * KK + 1];
        const float l2 = L[n * KK + 2];
        gL = l0 * gw0 + l1 * gw1 + l2 * gw2;
        bL = l0 * bw0 + l1 * bw1 + l2 * bw2;
    }
    const float aS  = gS + gGS * Gv;      // coeff of s in zpred
    const float aC  = gC + gGC * Gv;      // coeff of c in zpred
    const float a0  = gG * Gv + gL;       // const in zpred
    const float lS  = bS + bGS * Gv;      // coeff of s in logit
    const float l0c = b0 + bG * Gv + bL;  // const in logit

    float zm = 0.0f;   // Z_mean
    float zv = 1.0f;   // Z_var
    float ll = 0.0f;

    const float4* S4 = (const float4*)S;
    const float4* C4 = (const float4*)C;
    const float4* Y4 = (const float4*)Y;
    float4* Zf4 = (float4*)Zf;
    float4* Zv4 = (float4*)Zv;

    // Cooperative tile mapping: per array, NB*CT/4 = 1024 float4s; thread
    // handles j=0..3 with row r=(tid>>2)+64j, chunk c=tid&3 (64B-aligned
    // full-line coverage: lanes 4k..4k+3 cover one row's 64B).
    const int rb = tid >> 2;          // row base
    const int c  = tid & 3;           // float4 chunk within row tile
    const int xc = (c & 1) << 4;      // xor swizzle constant for scatter/gather
    const int tb = c * 4;             // first t of this chunk

    float4 rs[4], ry[4], rc[4];       // prefetch registers (tile k+1)
    const float4 z4 = make_float4(0, 0, 0, 0);

    // --- prefetch tile 0 ---
    {
        #pragma unroll
        for (int j = 0; j < 4; ++j) {
            const int nn = n0 + rb + 64 * j;
            const bool v = (nn < N);
            const int g = nn * (TT / 4) + c;
            rs[j] = v ? S4[g] : z4;
            ry[j] = v ? Y4[g] : z4;
            rc[j] = v ? C4[g] : z4;
        }
    }

    for (int k = 0; k < NTILES; ++k) {
        if (k) __syncthreads();   // prev store-phase gathers done

        // --- scatter prefetched regs -> LDS (packing S+2Y on the fly) ---
        #pragma unroll
        for (int j = 0; j < 4; ++j) {
            const int xr = (rb + 64 * j) ^ xc;
            const float4 vs = rs[j], vy = ry[j], vc = rc[j];
            sbuf[(tb + 0) * NB + xr] = fmaf(2.0f, vy.x, vs.x);
            sbuf[(tb + 1) * NB + xr] = fmaf(2.0f, vy.y, vs.y);
            sbuf[(tb + 2) * NB + xr] = fmaf(2.0f, vy.z, vs.z);
            sbuf[(tb + 3) * NB + xr] = fmaf(2.0f, vy.w, vs.w);
            cbuf[(tb + 0) * NB + xr] = vc.x;
            cbuf[(tb + 1) * NB + xr] = vc.y;
            cbuf[(tb + 2) * NB + xr] = vc.z;
            cbuf[(tb + 3) * NB + xr] = vc.w;
        }
        __syncthreads();

        // --- issue next tile's global loads (latency hidden by compute) ---
        if (k + 1 < NTILES) {
            const int tf = ((k + 1) * CT) >> 2;
            #pragma unroll
            for (int j = 0; j < 4; ++j) {
                const int nn = n0 + rb + 64 * j;
                const bool v = (nn < N);
                const int g = nn * (TT / 4) + tf + c;
                rs[j] = v ? S4[g] : z4;
                ry[j] = v ? Y4[g] : z4;
                rc[j] = v ? C4[g] : z4;
            }
        }

        // --- sequential filter over CT steps; stage outputs in place ---
        #pragma unroll
        for (int t = 0; t < CT; ++t) {
            const int idx = t * NB + (tid ^ (((t >> 2) & 1) << 4));
            const float psy = sbuf[idx];
            const float cc  = cbuf[idx];
            const float y = (psy > 1.5f) ? 1.0f : 0.0f;
            const float s = fmaf(-2.0f, y, psy);

            const float zpred = fmaf(psi, zm, fmaf(aS, s, fmaf(aC, cc, a0)));
            const float zpvar = fmaf(psi2, zv, sigma2);

            float logit = fmaf(bZ, zpred, fmaf(lS, s, l0c));
            logit = fminf(fmaxf(logit, -20.0f), 20.0f);
            const float p = __builtin_amdgcn_rcpf(1.0f + __expf(-logit));

            const float grad = (y - p) * bZ;
            const float hess = fmaf(bZ2, p * (1.0f - p), 1e-6f);
            const float zvn = zpvar * __builtin_amdgcn_rcpf(fmaf(zpvar, hess, 1.0f));
            const float zmn = fmaf(zvn, grad, zpred);

            // y in {0,1}: y*log(p+e)+(1-y)*log(1-p+e) == log((y?p:1-p)+e)
            const float sel = fmaf(y, fmaf(2.0f, p, -1.0f), 1.0f - p);
            ll += __logf(sel + 1e-10f);

            zm = zmn;
            zv = zvn;
            sbuf[idx] = zmn;   // stage Z_filtered
            cbuf[idx] = zvn;   // stage Z_variance
        }
        __syncthreads();

        // --- cooperative coalesced store of staged outputs ---
        {
            const int tf = (k * CT) >> 2;
            #pragma unroll
            for (int j = 0; j < 4; ++j) {
                const int nn = n0 + rb + 64 * j;
                if (nn < N) {
                    const int xr = (rb + 64 * j) ^ xc;
                    float4 vf, vv;
                    vf.x = sbuf[(tb + 0) * NB + xr];
                    vf.y = sbuf[(tb + 1) * NB + xr];
                    vf.z = sbuf[(tb + 2) * NB + xr];
                    vf.w = sbuf[(tb + 3) * NB + xr];
                    vv.x = cbuf[(tb + 0) * NB + xr];
                    vv.y = cbuf[(tb + 1) * NB + xr];
                    vv.z = cbuf[(tb + 2) * NB + xr];
                    vv.w = cbuf[(tb + 3) * NB + xr];
                    const int g = nn * (TT / 4) + tf + c;
                    Zf4[g] = vf;
                    Zv4[g] = vv;
                }
            }
        }
    }

    // --- log-likelihood: mask invalid, wave shuffle -> LDS -> one atomic ---
    if (!valid) ll = 0.0f;
    #pragma unroll
    for (int off = 32; off > 0; off >>= 1) {
        ll += __shfl_down(ll, off, 64);
    }
    __syncthreads();   // all store-phase LDS reads done before reuse
    if ((tid & 63) == 0) sbuf[tid >> 6] = ll;
    __syncthreads();
    if (tid == 0) {
        atomicAdd(ll_out, sbuf[0] + sbuf[1] + sbuf[2] + sbuf[3]);
    }
}

extern "C" void kernel_launch(void* const* d_in, const int* in_sizes, int n_in,
                              void* d_out, int out_size, void* d_ws, size_t ws_size,
                              hipStream_t stream) {
    const int N = in_sizes[0];  // G is (N,1)

    const float* G   = (const float*)d_in[0];
    const float* S   = (const float*)d_in[1];
    const float* C   = (const float*)d_in[2];
    const float* Y   = (const float*)d_in[3];
    const float* L   = (const float*)d_in[4];
    const float* psi = (const float*)d_in[5];
    const float* gS  = (const float*)d_in[6];
    const float* gC  = (const float*)d_in[7];
    const float* gG  = (const float*)d_in[8];
    const float* gGS = (const float*)d_in[9];
    const float* gGC = (const float*)d_in[10];
    const float* gLw = (const float*)d_in[11];
    const float* lsZ = (const float*)d_in[12];
    const float* b0  = (const float*)d_in[13];
    const float* bZ  = (const float*)d_in[14];
    const float* bS  = (const float*)d_in[15];
    const float* bG  = (const float*)d_in[16];
    const float* bGS = (const float*)d_in[17];
    const float* bLw = (const float*)d_in[18];

    float* out = (float*)d_out;
    float* Zf = out;
    float* Zv = out + (size_t)N * TT;
    float* ll = out + (size_t)2 * N * TT;

    zero_ll_kernel<<<1, 1, 0, stream>>>(ll);

    const int blocks = (N + NB - 1) / NB;
    hmm_filter_kernel<<<blocks, NB, 0, stream>>>(
        G, S, C, Y, L, psi, gS, gC, gG, gGS, gGC, gLw, lsZ,
        b0, bZ, bS, bG, bGS, bLw, Zf, Zv, ll, N);
}